// Round 1
// baseline (1112.794 us; speedup 1.0000x reference)
//
#include <hip/hip_runtime.h>
#include <hip/hip_bf16.h>
#include <math.h>

#define B_SZ 2
#define L_SZ 1024
#define DM 1024
#define DI 2048
#define NS 16
#define DTR 64

// ---------------- Tiled f32 GEMM: C[M,N] = A[M,K] @ B[K,N] ----------------
// 64x64 tile, BK=16, 256 threads, 4x4 micro-tile per thread.
__global__ __launch_bounds__(256) void gemm_f32(
    const float* __restrict__ A, int lda,
    const float* __restrict__ B, int ldb,
    float* __restrict__ C, int ldc, int K) {
  __shared__ float As[16][68];  // [k][m], padded
  __shared__ float Bs[16][68];  // [k][n], padded
  const int tid = threadIdx.x;
  const int tx = tid & 15;        // micro col group
  const int ty = tid >> 4;        // micro row group
  const int m0 = blockIdx.y * 64;
  const int n0 = blockIdx.x * 64;

  float acc[4][4];
#pragma unroll
  for (int i = 0; i < 4; ++i)
#pragma unroll
    for (int j = 0; j < 4; ++j) acc[i][j] = 0.f;

  for (int k0 = 0; k0 < K; k0 += 16) {
    // A tile: 64 rows x 16 cols -> As[k][m]
    {
      const int c = tid & 15;
      const int r0 = tid >> 4;
#pragma unroll
      for (int p = 0; p < 4; ++p) {
        const int r = r0 + p * 16;
        As[c][r] = A[(size_t)(m0 + r) * lda + k0 + c];
      }
    }
    // B tile: 16 rows x 64 cols -> Bs[k][n]
    {
      const int c = tid & 63;
      const int r0 = tid >> 6;
#pragma unroll
      for (int p = 0; p < 4; ++p) {
        const int r = r0 + p * 4;
        Bs[r][c] = B[(size_t)(k0 + r) * ldb + n0 + c];
      }
    }
    __syncthreads();
#pragma unroll
    for (int kk = 0; kk < 16; ++kk) {
      const float4 a4 = *(const float4*)&As[kk][ty * 4];
      const float4 b4 = *(const float4*)&Bs[kk][tx * 4];
      const float a[4] = {a4.x, a4.y, a4.z, a4.w};
      const float b[4] = {b4.x, b4.y, b4.z, b4.w};
#pragma unroll
      for (int i = 0; i < 4; ++i)
#pragma unroll
        for (int j = 0; j < 4; ++j) acc[i][j] = fmaf(a[i], b[j], acc[i][j]);
    }
    __syncthreads();
  }
#pragma unroll
  for (int i = 0; i < 4; ++i) {
    float4 v = make_float4(acc[i][0], acc[i][1], acc[i][2], acc[i][3]);
    *(float4*)&C[(size_t)(m0 + ty * 4 + i) * ldc + n0 + tx * 4] = v;
  }
}

// ------------- causal depthwise conv (k=4) + silu -> xc (2048x2048) -------------
__global__ __launch_bounds__(256) void conv_silu(
    const float* __restrict__ xz, const float* __restrict__ kern,
    const float* __restrict__ bias, float* __restrict__ xc) {
  const int d = blockIdx.y * 256 + threadIdx.x;  // 0..2047
  const int row = blockIdx.x;                    // b*L + l
  const int l = row & (L_SZ - 1);
  float acc = bias[d];
#pragma unroll
  for (int i = 0; i < 4; ++i) {
    const int li = l - 3 + i;
    if (li >= 0) acc = fmaf(xz[(size_t)(row - 3 + i) * 4096 + d], kern[i * DI + d], acc);
  }
  const float s = acc / (1.f + __expf(-acc));  // silu
  xc[(size_t)row * DI + d] = s;
}

// ------------- x_dbl = xc @ Wx : (2048 x 96), K=2048 -------------
__global__ __launch_bounds__(768) void gemm_xdbl(
    const float* __restrict__ xc, const float* __restrict__ Wx,
    float* __restrict__ xdbl) {
  const int col = threadIdx.x;                       // 0..95
  const int row = blockIdx.x * 8 + threadIdx.y;      // 0..2047
  const float* __restrict__ arow = xc + (size_t)row * DI;
  float acc = 0.f;
  for (int k = 0; k < DI; k += 4) {
    acc = fmaf(arow[k + 0], Wx[(k + 0) * 96 + col], acc);
    acc = fmaf(arow[k + 1], Wx[(k + 1) * 96 + col], acc);
    acc = fmaf(arow[k + 2], Wx[(k + 2) * 96 + col], acc);
    acc = fmaf(arow[k + 3], Wx[(k + 3) * 96 + col], acc);
  }
  xdbl[(size_t)row * 96 + col] = acc;
}

// ------------- delta = softplus(dt @ Wdt + dt_bias) : (2048 x 2048), K=64 -------------
__global__ __launch_bounds__(256) void gemm_delta(
    const float* __restrict__ xdbl, const float* __restrict__ Wdt,
    const float* __restrict__ dt_bias, float* __restrict__ delta) {
  const int col = blockIdx.x * 256 + threadIdx.x;  // 0..2047
  const int row = blockIdx.y;                      // 0..2047
  const float* __restrict__ dt = xdbl + (size_t)row * 96;
  float acc = dt_bias[col];
#pragma unroll
  for (int k = 0; k < DTR; ++k) acc = fmaf(dt[k], Wdt[(size_t)k * DI + col], acc);
  const float sp = (acc > 20.f) ? acc : log1pf(__expf(acc));
  delta[(size_t)row * DI + col] = sp;
}

// ------------- selective scan, fused skip + silu(z) gate -------------
// One thread per (b, d, n). 64-thread blocks: 4 d-channels x 16 states.
// y written into the (dead) x half of xz, stride 4096.
__global__ __launch_bounds__(64) void scan_kernel(
    const float* __restrict__ delta, const float* __restrict__ xc,
    const float* __restrict__ xdbl, const float* __restrict__ A_log,
    const float* __restrict__ Dskip, float* __restrict__ xz) {
  const int blk = blockIdx.x;   // 0..1023
  const int b = blk >> 9;       // 512 blocks per batch
  const int dgrp = blk & 511;
  const int lane = threadIdx.x; // 0..63
  const int n = lane & 15;
  const int d = dgrp * 4 + (lane >> 4);

  const float Aval = -__expf(A_log[d * NS + n]);
  const float Dsk = Dskip[d];
  float x = 0.f;

  const int CH = 8;
  for (int l0 = 0; l0 < L_SZ; l0 += CH) {
    float dlt[8], u[8], Bv[8], Cv[8];
#pragma unroll
    for (int j = 0; j < CH; ++j) {
      const int row = b * L_SZ + l0 + j;
      dlt[j] = delta[(size_t)row * DI + d];
      u[j] = xc[(size_t)row * DI + d];
      Bv[j] = xdbl[(size_t)row * 96 + 64 + n];
      Cv[j] = xdbl[(size_t)row * 96 + 80 + n];
    }
#pragma unroll
    for (int j = 0; j < CH; ++j) {
      const int row = b * L_SZ + l0 + j;
      const float dA = __expf(dlt[j] * Aval);
      x = fmaf(dA, x, dlt[j] * Bv[j] * u[j]);
      float p = x * Cv[j];
      p += __shfl_xor(p, 8);
      p += __shfl_xor(p, 4);
      p += __shfl_xor(p, 2);
      p += __shfl_xor(p, 1);
      if (n == 0) {
        const float zv = xz[(size_t)row * 4096 + DI + d];
        const float yv = p + u[j] * Dsk;
        const float sz = zv / (1.f + __expf(-zv));
        xz[(size_t)row * 4096 + d] = yv * sz;
      }
    }
  }
}

extern "C" void kernel_launch(void* const* d_in, const int* in_sizes, int n_in,
                              void* d_out, int out_size, void* d_ws, size_t ws_size,
                              hipStream_t stream) {
  const float* hidden  = (const float*)d_in[0];  // (2, 1024, 1024)
  const float* Win     = (const float*)d_in[1];  // (1024, 4096)
  const float* Wx      = (const float*)d_in[2];  // (2048, 96)
  const float* Wdt     = (const float*)d_in[3];  // (64, 2048)
  const float* dt_bias = (const float*)d_in[4];  // (2048,)
  const float* Wout    = (const float*)d_in[5];  // (2048, 1024)
  const float* dwk     = (const float*)d_in[6];  // (4, 2048)
  const float* dwb     = (const float*)d_in[7];  // (2048,)
  const float* A_log   = (const float*)d_in[8];  // (2048, 16)
  const float* Dskip   = (const float*)d_in[9];  // (2048,)
  float* out = (float*)d_out;                    // (2048, 1024)

  char* ws = (char*)d_ws;
  float* xz    = (float*)(ws);                    // 2048 x 4096 (x | z); x half reused for y
  float* xc    = (float*)(ws + 33554432);         // 2048 x 2048
  float* xdbl  = (float*)(ws + 50331648);         // 2048 x 96
  float* delta = (float*)(ws + 51118080);         // 2048 x 2048

  // xz = hidden @ Win   (M=2048, N=4096, K=1024)
  gemm_f32<<<dim3(4096 / 64, 2048 / 64), 256, 0, stream>>>(
      hidden, DM, Win, 2 * DI, xz, 2 * DI, DM);
  // depthwise causal conv + silu
  conv_silu<<<dim3(B_SZ * L_SZ, DI / 256), 256, 0, stream>>>(xz, dwk, dwb, xc);
  // x_dbl = xc @ Wx
  gemm_xdbl<<<dim3(B_SZ * L_SZ / 8), dim3(96, 8), 0, stream>>>(xc, Wx, xdbl);
  // delta = softplus(dt @ Wdt + bias)
  gemm_delta<<<dim3(DI / 256, B_SZ * L_SZ), 256, 0, stream>>>(xdbl, Wdt, dt_bias, delta);
  // selective scan + skip + gate, y -> xz[:, 0:2048]
  scan_kernel<<<dim3(B_SZ * (DI / 4)), 64, 0, stream>>>(delta, xc, xdbl, A_log, Dskip, xz);
  // out = y @ Wout   (M=2048, N=1024, K=2048), A has lda=4096
  gemm_f32<<<dim3(1024 / 64, 2048 / 64), 256, 0, stream>>>(
      xz, 2 * DI, Wout, DM, out, DM, DI);
}

// Round 2
// 472.634 us; speedup vs baseline: 2.3545x; 2.3545x over previous
//
#include <hip/hip_runtime.h>
#include <hip/hip_bf16.h>
#include <math.h>

#define B_SZ 2
#define L_SZ 1024
#define DM 1024
#define DI 2048
#define NS 16
#define DTR 64
#define NCHUNK 8
#define CLEN 128

typedef unsigned short ushortT;
typedef __attribute__((ext_vector_type(8))) short short8;
typedef __attribute__((ext_vector_type(4))) float floatx4;

__device__ __forceinline__ ushortT f2bf(float f) {
  unsigned u = __float_as_uint(f);
  unsigned r = (u + 0x7fff + ((u >> 16) & 1)) >> 16;
  return (ushortT)r;
}

__device__ __forceinline__ void gl2lds16(const void* g, void* l) {
  __builtin_amdgcn_global_load_lds(
      (const __attribute__((address_space(1))) unsigned int*)g,
      (__attribute__((address_space(3))) unsigned int*)l, 16, 0, 0);
}

// ---------------- f32 -> bf16 convert (4 elems/thread) ----------------
__global__ __launch_bounds__(256) void cvt_bf16(const float* __restrict__ src,
                                                ushortT* __restrict__ dst) {
  const int i = blockIdx.x * 256 + threadIdx.x;
  float4 v = ((const float4*)src)[i];
  unsigned lo = (unsigned)f2bf(v.x) | ((unsigned)f2bf(v.y) << 16);
  unsigned hi = (unsigned)f2bf(v.z) | ((unsigned)f2bf(v.w) << 16);
  ((uint2*)dst)[i] = make_uint2(lo, hi);
}

// ---------------- f32 [R][C] -> bf16 [C][R] transpose ----------------
__global__ __launch_bounds__(256) void transpose_bf16(
    const float* __restrict__ src, ushortT* __restrict__ dst, int R, int C) {
  __shared__ float t[32][33];
  const int bx = blockIdx.x * 32;  // col base
  const int by = blockIdx.y * 32;  // row base
  const int tx = threadIdx.x, ty = threadIdx.y;  // (32,8)
#pragma unroll
  for (int j = 0; j < 4; ++j)
    t[ty + j * 8][tx] = src[(size_t)(by + ty + j * 8) * C + bx + tx];
  __syncthreads();
#pragma unroll
  for (int j = 0; j < 4; ++j)
    dst[(size_t)(bx + ty + j * 8) * R + by + tx] = f2bf(t[tx][ty + j * 8]);
}

// ---------------- bf16 MFMA GEMM: C[M][N] f32 = A[M][K] @ BT[N][K]^T ----------------
// m97-style: BK=32, global_load_lds width=16, XOR chunk swizzle, 16x16x32 MFMA.
template <int BM, int BN>
__global__ __launch_bounds__((BM / 64) * (BN / 64) * 64) void gemm_bf16(
    const ushortT* __restrict__ A, int lda,
    const ushortT* __restrict__ BT, int ldb,
    float* __restrict__ C, int ldc, int K) {
  constexpr int NW = (BM / 64) * (BN / 64);
  constexpr int NT = NW * 64;
  __shared__ __align__(16) char smem[(BM + BN) * 64];
  char* As = smem;
  char* Bs = smem + BM * 64;
  const int tid = threadIdx.x;
  const int lane = tid & 63;
  const int quad = lane >> 4;
  const int l16 = lane & 15;
  const int wid = tid >> 6;
  const int wm = wid % (BM / 64);
  const int wn = wid / (BM / 64);
  const int m0 = blockIdx.y * BM;
  const int n0 = blockIdx.x * BN;

  floatx4 acc[4][4] = {};

  for (int k0 = 0; k0 < K; k0 += 32) {
    // stage A tile: BM rows x 64B, chunk-swizzled
    for (int i = tid; i < BM * 4; i += NT) {
      const int r = i >> 2, c = i & 3;
      const int cg = c ^ (r & 3);
      const char* g = (const char*)(A + (size_t)(m0 + r) * lda + k0) + cg * 16;
      gl2lds16(g, As + (size_t)(i - lane) * 16);
    }
    // stage B tile: BN rows x 64B
    for (int i = tid; i < BN * 4; i += NT) {
      const int r = i >> 2, c = i & 3;
      const int cg = c ^ (r & 3);
      const char* g = (const char*)(BT + (size_t)(n0 + r) * ldb + k0) + cg * 16;
      gl2lds16(g, Bs + (size_t)(i - lane) * 16);
    }
    __syncthreads();

    short8 afr[4], bfr[4];
#pragma unroll
    for (int i = 0; i < 4; ++i) {
      const int r = wm * 64 + i * 16 + l16;
      afr[i] = *(const short8*)(As + r * 64 + ((quad ^ (r & 3)) * 16));
    }
#pragma unroll
    for (int j = 0; j < 4; ++j) {
      const int r = wn * 64 + j * 16 + l16;
      bfr[j] = *(const short8*)(Bs + r * 64 + ((quad ^ (r & 3)) * 16));
    }
#pragma unroll
    for (int i = 0; i < 4; ++i)
#pragma unroll
      for (int j = 0; j < 4; ++j)
        acc[i][j] = __builtin_amdgcn_mfma_f32_16x16x32_bf16(afr[i], bfr[j],
                                                            acc[i][j], 0, 0, 0);
    __syncthreads();
  }
  // epilogue: C/D layout col=lane&15, row=quad*4+reg
#pragma unroll
  for (int i = 0; i < 4; ++i)
#pragma unroll
    for (int j = 0; j < 4; ++j)
#pragma unroll
      for (int r = 0; r < 4; ++r) {
        const int m = m0 + wm * 64 + i * 16 + quad * 4 + r;
        const int n = n0 + wn * 64 + j * 16 + l16;
        C[(size_t)m * ldc + n] = acc[i][j][r];
      }
}

// ------------- causal depthwise conv (k=4) + silu -> xc f32 -------------
__global__ __launch_bounds__(256) void conv_silu(
    const float* __restrict__ xz, const float* __restrict__ kern,
    const float* __restrict__ bias, float* __restrict__ xc) {
  const int d = blockIdx.y * 256 + threadIdx.x;
  const int row = blockIdx.x;
  const int l = row & (L_SZ - 1);
  float acc = bias[d];
#pragma unroll
  for (int i = 0; i < 4; ++i) {
    const int li = l - 3 + i;
    if (li >= 0) acc = fmaf(xz[(size_t)(row - 3 + i) * 4096 + d], kern[i * DI + d], acc);
  }
  xc[(size_t)row * DI + d] = acc / (1.f + __expf(-acc));
}

// ------------- x_dbl = xc @ Wx : (2048 x 96), K=2048 -------------
__global__ __launch_bounds__(768) void gemm_xdbl(
    const float* __restrict__ xc, const float* __restrict__ Wx,
    float* __restrict__ xdbl) {
  const int col = threadIdx.x;
  const int row = blockIdx.x * 8 + threadIdx.y;
  const float* __restrict__ arow = xc + (size_t)row * DI;
  float acc = 0.f;
  for (int k = 0; k < DI; k += 4) {
    acc = fmaf(arow[k + 0], Wx[(k + 0) * 96 + col], acc);
    acc = fmaf(arow[k + 1], Wx[(k + 1) * 96 + col], acc);
    acc = fmaf(arow[k + 2], Wx[(k + 2) * 96 + col], acc);
    acc = fmaf(arow[k + 3], Wx[(k + 3) * 96 + col], acc);
  }
  xdbl[(size_t)row * 96 + col] = acc;
}

// ------------- delta = softplus(dt @ Wdt + dt_bias) -------------
__global__ __launch_bounds__(256) void gemm_delta(
    const float* __restrict__ xdbl, const float* __restrict__ Wdt,
    const float* __restrict__ dt_bias, float* __restrict__ delta) {
  const int col = blockIdx.x * 256 + threadIdx.x;
  const int row = blockIdx.y;
  const float* __restrict__ dt = xdbl + (size_t)row * 96;
  float acc = dt_bias[col];
#pragma unroll
  for (int k = 0; k < DTR; ++k) acc = fmaf(dt[k], Wdt[(size_t)k * DI + col], acc);
  delta[(size_t)row * DI + col] = (acc > 20.f) ? acc : log1pf(__expf(acc));
}

// ------------- scan phase 1: per-chunk transition (prod dA, local final state) -------------
// blocks: b(1) | chunk(3) | dtile(3); 256 threads = contiguous d.
__global__ __launch_bounds__(256) void scan_phase1(
    const float* __restrict__ delta, const float* __restrict__ xc,
    const float* __restrict__ xdbl, const float* __restrict__ A_log,
    float* __restrict__ aprod, float* __restrict__ sfin) {
  const int bx = blockIdx.x;
  const int b = bx >> 6;
  const int c = (bx >> 3) & 7;
  const int d = (bx & 7) * 256 + threadIdx.x;
  const int row0 = b * L_SZ + c * CLEN;

  __shared__ float Bsh[CLEN][16];
  for (int i = threadIdx.x; i < CLEN * 16; i += 256) {
    const int r = i >> 4, n = i & 15;
    Bsh[r][n] = xdbl[(size_t)(row0 + r) * 96 + 64 + n];
  }

  float Av[16];
#pragma unroll
  for (int n = 0; n < 16; ++n) Av[n] = -__expf(A_log[d * 16 + n]);
  float x[16] = {}, P[16];
#pragma unroll
  for (int n = 0; n < 16; ++n) P[n] = 1.f;

  __syncthreads();

  const float* dp = delta + (size_t)row0 * DI + d;
  const float* up = xc + (size_t)row0 * DI + d;
  float dlt = dp[0], u = up[0];
  for (int l = 0; l < CLEN; ++l) {
    float dn = 0.f, un = 0.f;
    if (l + 1 < CLEN) { dn = dp[(size_t)(l + 1) * DI]; un = up[(size_t)(l + 1) * DI]; }
    const float t = dlt * u;
#pragma unroll
    for (int n = 0; n < 16; ++n) {
      const float dA = __expf(dlt * Av[n]);
      P[n] *= dA;
      x[n] = fmaf(dA, x[n], t * Bsh[l][n]);
    }
    dlt = dn; u = un;
  }
  const size_t sb = (((size_t)(b * NCHUNK + c) * DI) + d) * 16;
#pragma unroll
  for (int n = 0; n < 16; ++n) { aprod[sb + n] = P[n]; sfin[sb + n] = x[n]; }
}

// ------------- scan phase 2: sequential chunk combine; sfin becomes xinit -------------
__global__ __launch_bounds__(256) void scan_phase2(
    const float* __restrict__ aprod, float* __restrict__ sfin) {
  const int t = blockIdx.x * 256 + threadIdx.x;  // (b, d, n) flat
  const int b = t >> 15;
  const int rem = t & 32767;
  float x = 0.f;
#pragma unroll
  for (int c = 0; c < NCHUNK; ++c) {
    const size_t idx = ((size_t)(b * NCHUNK + c) << 15) + rem;
    const float P = aprod[idx];
    const float S = sfin[idx];
    sfin[idx] = x;           // xinit for chunk c
    x = fmaf(P, x, S);
  }
}

// ------------- scan phase 3: rescan w/ init state + y + skip + gate -> bf16 y in xz x-half -------------
__global__ __launch_bounds__(256) void scan_phase3(
    const float* __restrict__ delta, const float* __restrict__ xc,
    const float* __restrict__ xdbl, const float* __restrict__ A_log,
    const float* __restrict__ Dskip, const float* __restrict__ xinit,
    float* __restrict__ xz) {
  const int bx = blockIdx.x;
  const int b = bx >> 6;
  const int c = (bx >> 3) & 7;
  const int d = (bx & 7) * 256 + threadIdx.x;
  const int row0 = b * L_SZ + c * CLEN;

  __shared__ float Bsh[CLEN][16], Csh[CLEN][16];
  for (int i = threadIdx.x; i < CLEN * 32; i += 256) {
    const int r = i >> 5, q = i & 31;
    const float v = xdbl[(size_t)(row0 + r) * 96 + 64 + q];
    if (q < 16) Bsh[r][q] = v; else Csh[r][q - 16] = v;
  }

  float Av[16];
#pragma unroll
  for (int n = 0; n < 16; ++n) Av[n] = -__expf(A_log[d * 16 + n]);
  const float Dsk = Dskip[d];
  const size_t sb = (((size_t)(b * NCHUNK + c) * DI) + d) * 16;
  float x[16];
#pragma unroll
  for (int n = 0; n < 16; ++n) x[n] = xinit[sb + n];

  __syncthreads();

  const float* dp = delta + (size_t)row0 * DI + d;
  const float* up = xc + (size_t)row0 * DI + d;
  ushortT* yb = (ushortT*)xz;
  float dlt = dp[0], u = up[0];
  for (int l = 0; l < CLEN; ++l) {
    float dn = 0.f, un = 0.f;
    if (l + 1 < CLEN) { dn = dp[(size_t)(l + 1) * DI]; un = up[(size_t)(l + 1) * DI]; }
    const float t = dlt * u;
    float y = 0.f;
#pragma unroll
    for (int n = 0; n < 16; ++n) {
      const float dA = __expf(dlt * Av[n]);
      x[n] = fmaf(dA, x[n], t * Bsh[l][n]);
      y = fmaf(x[n], Csh[l][n], y);
    }
    const size_t row = (size_t)(row0 + l);
    const float z = xz[row * 4096 + DI + d];
    const float g = (y + u * Dsk) * (z / (1.f + __expf(-z)));
    yb[row * 8192 + d] = f2bf(g);
    dlt = dn; u = un;
  }
}

extern "C" void kernel_launch(void* const* d_in, const int* in_sizes, int n_in,
                              void* d_out, int out_size, void* d_ws, size_t ws_size,
                              hipStream_t stream) {
  const float* hidden  = (const float*)d_in[0];
  const float* Win     = (const float*)d_in[1];
  const float* Wx      = (const float*)d_in[2];
  const float* Wdt     = (const float*)d_in[3];
  const float* dt_bias = (const float*)d_in[4];
  const float* Wout    = (const float*)d_in[5];
  const float* dwk     = (const float*)d_in[6];
  const float* dwb     = (const float*)d_in[7];
  const float* A_log   = (const float*)d_in[8];
  const float* Dskip   = (const float*)d_in[9];

  // ws (64 MB): xz 32MB | shared16 (WinT -> delta -> WoutT) 16MB | xc 16MB
  char* ws = (char*)d_ws;
  float* xz       = (float*)ws;
  float* shared16 = (float*)(ws + (32u << 20));
  float* xc       = (float*)(ws + (48u << 20));
  // d_out (8 MB) doubles as scratch: hid_bf16 [0,4M) -> stats [0,4M); xdbl [4M,4.75M)
  char* dob = (char*)d_out;
  ushortT* hidb = (ushortT*)dob;
  float* xdbl   = (float*)(dob + (4u << 20));
  float* aprod  = (float*)dob;
  float* sfin   = (float*)(dob + (2u << 20));

  // 1. hidden -> bf16 (into d_out)
  cvt_bf16<<<dim3(B_SZ * L_SZ * DM / 1024), 256, 0, stream>>>(hidden, hidb);
  // 2. Win (1024x4096) -> WinT bf16 (4096x1024) in shared16
  transpose_bf16<<<dim3(4096 / 32, 1024 / 32), dim3(32, 8), 0, stream>>>(
      Win, (ushortT*)shared16, DM, 2 * DI);
  // 3. GEMM1: xz = hidden @ Win  (M=2048, N=4096, K=1024)
  gemm_bf16<128, 128><<<dim3(4096 / 128, 2048 / 128), 256, 0, stream>>>(
      hidb, DM, (ushortT*)shared16, DM, xz, 2 * DI, DM);
  // 4. depthwise conv + silu -> xc
  conv_silu<<<dim3(B_SZ * L_SZ, DI / 256), 256, 0, stream>>>(xz, dwk, dwb, xc);
  // 5. x_dbl = xc @ Wx (into d_out scratch)
  gemm_xdbl<<<dim3(B_SZ * L_SZ / 8), dim3(96, 8), 0, stream>>>(xc, Wx, xdbl);
  // 6. delta = softplus(dt @ Wdt + bias) -> shared16 (WinT dead)
  gemm_delta<<<dim3(DI / 256, B_SZ * L_SZ), 256, 0, stream>>>(xdbl, Wdt, dt_bias, shared16);
  // 7-9. chunked selective scan; y (gated, bf16) -> xz x-half
  scan_phase1<<<dim3(B_SZ * NCHUNK * (DI / 256)), 256, 0, stream>>>(
      shared16, xc, xdbl, A_log, aprod, sfin);
  scan_phase2<<<dim3(B_SZ * DI * NS / 256), 256, 0, stream>>>(aprod, sfin);
  scan_phase3<<<dim3(B_SZ * NCHUNK * (DI / 256)), 256, 0, stream>>>(
      shared16, xc, xdbl, A_log, Dskip, sfin, xz);
  // 10. Wout (2048x1024) -> WoutT bf16 (1024x2048) in shared16 (delta dead)
  transpose_bf16<<<dim3(1024 / 32, 2048 / 32), dim3(32, 8), 0, stream>>>(
      Wout, (ushortT*)shared16, DI, DM);
  // 11. GEMM4: out = y @ Wout  (M=2048, N=1024, K=2048); A = bf16 y, lda=8192
  gemm_bf16<128, 64><<<dim3(1024 / 64, 2048 / 128), 128, 0, stream>>>(
      (ushortT*)xz, 4 * DI, (ushortT*)shared16, DI, (float*)d_out, DM, DI);
}